// Round 14
// baseline (243.207 us; speedup 1.0000x reference)
//
#include <hip/hip_runtime.h>
#include <stdint.h>

// FANeuron fused scan+emit, single launch:
//  - scan role (blockIdx < NG): round-11 structure — 64 chains/block, DEPTH-2
//    global_load_lds ring with counted vmcnt(16), hand-scheduled 6-instr/step
//    asm pipeline, 32-step window-bitmap refractory (rs>=31). Runs at
//    s_setprio(3). Every 4 tiles: store (ema,nr) seeds, release-fence (one
//    ring drain per chunk), set per-(chunk,group) flag.
//  - emit role: one block per (chunk, 64-chain group); polls its ONE flag
//    with RELAXED loads + s_sleep backoff (no coherence storm), one acquire
//    fence, then round-11 emit body (bit-exact replay, va_trace + spikes).
//  Producers never wait on consumers -> no deadlock under any placement.

#define LCHUNK 256
#define TS 64
#define K2_UNROLL 8

typedef const __attribute__((address_space(1))) uint32_t* gptr_t;
typedef __attribute__((address_space(3))) uint32_t* lptr_t;

// 8 bit-exact steps, hand-pipelined (round 11). ema/bits carried; vcc clobbered.
#define FA_ASM8(A)                                                         \
    asm volatile(                                                          \
        "v_sub_f32 %[d1], %[a0], %[ema]\n\t"                               \
        "v_mul_f32 %[am], %[al], %[d1]\n\t"                                \
        "v_add_f32 %[ema], %[ema], %[am]\n\t"                              \
        "v_sub_f32 %[d1], %[a1], %[ema]\n\t"                               \
        "v_sub_f32 %[d2], %[a0], %[ema]\n\t"                               \
        "v_mul_f32 %[am], %[al], %[d1]\n\t"                                \
        "v_cmp_le_f32_e64 vcc, %[th], |%[d2]|\n\t"                         \
        "v_add_f32 %[ema], %[ema], %[am]\n\t"                              \
        "v_addc_co_u32 %[bits], vcc, %[bits], %[bits], vcc\n\t"            \
        "v_sub_f32 %[d1], %[a2], %[ema]\n\t"                               \
        "v_sub_f32 %[d2], %[a1], %[ema]\n\t"                               \
        "v_mul_f32 %[am], %[al], %[d1]\n\t"                                \
        "v_cmp_le_f32_e64 vcc, %[th], |%[d2]|\n\t"                         \
        "v_add_f32 %[ema], %[ema], %[am]\n\t"                              \
        "v_addc_co_u32 %[bits], vcc, %[bits], %[bits], vcc\n\t"            \
        "v_sub_f32 %[d1], %[a3], %[ema]\n\t"                               \
        "v_sub_f32 %[d2], %[a2], %[ema]\n\t"                               \
        "v_mul_f32 %[am], %[al], %[d1]\n\t"                                \
        "v_cmp_le_f32_e64 vcc, %[th], |%[d2]|\n\t"                         \
        "v_add_f32 %[ema], %[ema], %[am]\n\t"                              \
        "v_addc_co_u32 %[bits], vcc, %[bits], %[bits], vcc\n\t"            \
        "v_sub_f32 %[d1], %[a4], %[ema]\n\t"                               \
        "v_sub_f32 %[d2], %[a3], %[ema]\n\t"                               \
        "v_mul_f32 %[am], %[al], %[d1]\n\t"                                \
        "v_cmp_le_f32_e64 vcc, %[th], |%[d2]|\n\t"                         \
        "v_add_f32 %[ema], %[ema], %[am]\n\t"                              \
        "v_addc_co_u32 %[bits], vcc, %[bits], %[bits], vcc\n\t"            \
        "v_sub_f32 %[d1], %[a5], %[ema]\n\t"                               \
        "v_sub_f32 %[d2], %[a4], %[ema]\n\t"                               \
        "v_mul_f32 %[am], %[al], %[d1]\n\t"                                \
        "v_cmp_le_f32_e64 vcc, %[th], |%[d2]|\n\t"                         \
        "v_add_f32 %[ema], %[ema], %[am]\n\t"                              \
        "v_addc_co_u32 %[bits], vcc, %[bits], %[bits], vcc\n\t"            \
        "v_sub_f32 %[d1], %[a6], %[ema]\n\t"                               \
        "v_sub_f32 %[d2], %[a5], %[ema]\n\t"                               \
        "v_mul_f32 %[am], %[al], %[d1]\n\t"                                \
        "v_cmp_le_f32_e64 vcc, %[th], |%[d2]|\n\t"                         \
        "v_add_f32 %[ema], %[ema], %[am]\n\t"                              \
        "v_addc_co_u32 %[bits], vcc, %[bits], %[bits], vcc\n\t"            \
        "v_sub_f32 %[d1], %[a7], %[ema]\n\t"                               \
        "v_sub_f32 %[d2], %[a6], %[ema]\n\t"                               \
        "v_mul_f32 %[am], %[al], %[d1]\n\t"                                \
        "v_cmp_le_f32_e64 vcc, %[th], |%[d2]|\n\t"                         \
        "v_add_f32 %[ema], %[ema], %[am]\n\t"                              \
        "v_addc_co_u32 %[bits], vcc, %[bits], %[bits], vcc\n\t"            \
        "v_sub_f32 %[d2], %[a7], %[ema]\n\t"                               \
        "v_cmp_le_f32_e64 vcc, %[th], |%[d2]|\n\t"                         \
        "v_addc_co_u32 %[bits], vcc, %[bits], %[bits], vcc"                \
        : [ema]"+v"(ema), [bits]"+v"(bits),                                \
          [d1]"=&v"(td1), [d2]"=&v"(td2), [am]"=&v"(tam)                   \
        : [a0]"v"((A)[0]), [a1]"v"((A)[1]), [a2]"v"((A)[2]),               \
          [a3]"v"((A)[3]), [a4]"v"((A)[4]), [a5]"v"((A)[5]),               \
          [a6]"v"((A)[6]), [a7]"v"((A)[7]),                                \
          [th]"v"(thf), [al]"s"(alpha)                                     \
        : "vcc")

#define FA_RESOLVE(BASE)                                                   \
    do {                                                                   \
        uint32_t rv = __brev(bits);                                        \
        int rel = nr - (BASE);                                             \
        uint32_t keep = (rel <= 0) ? rv                                    \
                      : ((rel >= 32) ? 0u : (rv & (0xFFFFFFFFu << rel)));  \
        int j1 = __ffs(keep);                                              \
        nr = keep ? ((BASE) + j1 + rs) : nr;                               \
        bits = 0;                                                          \
    } while (0)

__global__ __launch_bounds__(64)
void fa_fused_kernel(const float* __restrict__ x,
                     const float* __restrict__ vb,
                     const float* __restrict__ A,
                     const float* __restrict__ th,
                     const float* __restrict__ gain,
                     const float* __restrict__ tref,
                     float* __restrict__ emas,   // [nchunks][N]
                     int*   __restrict__ nrs,    // [nchunks][N]
                     int*   __restrict__ done,   // [nchunks][NG]
                     float* __restrict__ out,
                     int B, int T, int F, int nchunks, int NG) {
#pragma clang fp contract(off)
    __shared__ float lds[2][TS][64];             // 32 KiB
    const int N = B * F;
    const float alpha = 0.001f;                  // f32(0.05/50)
    const int lane = threadIdx.x;

    if ((int)blockIdx.x < NG) {
        // ================= scan role =================
        __builtin_amdgcn_s_setprio(3);
        const int g = blockIdx.x;
        const int gpb = F >> 6;
        const int b = g / gpb;
        const int f0 = (g - b * gpb) << 6;
        const int f = f0 + lane;
        const int i = b * F + f;

        const float vbf = vb[f], Af = A[f], thf = th[f], gf = gain[f];
        const int rs = (int)fmaxf(ceilf(tref[f] / 0.05f), 1.0f);

        const float* gsrc0 = x + (size_t)b * T * F + f0
                           + (size_t)(lane >> 4) * F + ((lane & 15) << 2);
        const int ntiles = T / TS;

#define ISSUE_TILE(J)                                                         \
    do {                                                                      \
        const float* s_ = gsrc0 + (size_t)(J) * TS * F;                       \
        float* d_ = &lds[(J) & 1][0][0];                                      \
        _Pragma("unroll")                                                     \
        for (int jj = 0; jj < 16; ++jj) {                                     \
            __builtin_amdgcn_global_load_lds(                                 \
                (gptr_t)(s_ + (size_t)(4 * jj) * F),                          \
                (lptr_t)(d_ + 4 * jj * 64), 16, 0, 0);                        \
        }                                                                     \
    } while (0)

        ISSUE_TILE(0);
        ISSUE_TILE(1);

        bool fastAll = __all((gf == 1.0f) && (Af == 1.0f) && (vbf == 0.0f) &&
                             (rs >= 31));

        float ema = 0.0f;
        int nr = 0;
        uint32_t bits = 0;
        float td1, td2, tam;

        for (int k = 0; k < ntiles; ++k) {
            if (k < ntiles - 1) asm volatile("s_waitcnt vmcnt(16)" ::: "memory");
            else                asm volatile("s_waitcnt vmcnt(0)"  ::: "memory");
            __builtin_amdgcn_sched_barrier(0);

            const int slot = k & 1;
            const int tb = k * TS;

            if (k == 0) {
                // bit-exact t==0 seeding: ema = xt(0)
                float x0 = lds[0][0][lane];
                ema = fastAll ? x0 : (x0 * gf);
            } else if ((k & 3) == 0) {           // LCHUNK/TS == 4
                int c = k >> 2;
                emas[(size_t)c * N + i] = ema;
                nrs[(size_t)c * N + i] = nr;
                __builtin_amdgcn_fence(__ATOMIC_RELEASE, "agent");
                if (lane == 0)
                    __hip_atomic_store(&done[c * NG + g], 1, __ATOMIC_RELAXED,
                                       __HIP_MEMORY_SCOPE_AGENT);
            }

            if (fastAll) {
                float Ab[8], Bb[8];
#pragma unroll
                for (int j = 0; j < 8; ++j) Ab[j] = lds[slot][j][lane];
#pragma unroll
                for (int j = 0; j < 8; ++j) Bb[j] = lds[slot][8 + j][lane];
                FA_ASM8(Ab);
#pragma unroll
                for (int j = 0; j < 8; ++j) Ab[j] = lds[slot][16 + j][lane];
                FA_ASM8(Bb);
#pragma unroll
                for (int j = 0; j < 8; ++j) Bb[j] = lds[slot][24 + j][lane];
                FA_ASM8(Ab);
#pragma unroll
                for (int j = 0; j < 8; ++j) Ab[j] = lds[slot][32 + j][lane];
                FA_ASM8(Bb);
                FA_RESOLVE(tb);
#pragma unroll
                for (int j = 0; j < 8; ++j) Bb[j] = lds[slot][40 + j][lane];
                FA_ASM8(Ab);
#pragma unroll
                for (int j = 0; j < 8; ++j) Ab[j] = lds[slot][48 + j][lane];
                FA_ASM8(Bb);
#pragma unroll
                for (int j = 0; j < 8; ++j) Bb[j] = lds[slot][56 + j][lane];
                FA_ASM8(Ab);
                FA_ASM8(Bb);
                FA_RESOLVE(tb + 32);
            } else {
                float ra[8], rb[8];
#pragma unroll
                for (int j = 0; j < 8; ++j) ra[j] = lds[slot][j][lane];
#pragma unroll
                for (int t8 = 0; t8 < TS / 8; ++t8) {
                    if (t8 < TS / 8 - 1) {
#pragma unroll
                        for (int j = 0; j < 8; ++j)
                            rb[j] = lds[slot][(t8 + 1) * 8 + j][lane];
                    }
#pragma unroll
                    for (int j = 0; j < 8; ++j) {
                        const int t = tb + t8 * 8 + j;
                        float xt = ra[j] * gf;
                        float d1 = xt - ema;
                        float am = alpha * d1;
                        ema = ema + am;
                        float d2 = xt - ema;
                        float av = Af * d2;
                        float vc = vbf - av;
                        float dv = vc - vbf;
                        bool cross = fabsf(dv) >= thf;
                        bool tge = t >= nr;
                        bool fired = cross && tge;
                        nr = fired ? (t + 1 + rs) : nr;
                    }
#pragma unroll
                    for (int j = 0; j < 8; ++j) ra[j] = rb[j];
                }
            }

            if (k + 2 < ntiles) ISSUE_TILE(k + 2);
        }
#undef ISSUE_TILE
    } else {
        // ================= emit role =================
        const int e = (int)blockIdx.x - NG;
        const int k = e / NG;                    // chunk (chunk-major dispatch)
        const int g = e - k * NG;
        const int i = g * 64 + lane;             // = b*F + f
        const int f = i % F;
        const int b = i / F;

        const float vbf = vb[f], Af = A[f], thf = th[f], gf = gain[f];
        const int rs = (int)fmaxf(ceilf(tref[f] / 0.05f), 1.0f);

        const float* xp = x + (size_t)b * T * F + f;
        float* va_out   = out + (size_t)b * (T + 1) * F + f;
        float* sp_out   = out + (size_t)B * (T + 1) * F + (size_t)b * (T + 1) * F + f;

        if (k > 0) {
            const int* flag = &done[k * NG + g];
            while (__hip_atomic_load(flag, __ATOMIC_RELAXED,
                                     __HIP_MEMORY_SCOPE_AGENT) == 0)
                __builtin_amdgcn_s_sleep(64);
            __builtin_amdgcn_fence(__ATOMIC_ACQUIRE, "agent");
        }

        const int tbeg = k * LCHUNK;
        int tend = tbeg + LCHUNK;
        if (tend > T) tend = T;

        float cur[K2_UNROLL], nxt[K2_UNROLL];
#pragma unroll
        for (int u = 0; u < K2_UNROLL; ++u) cur[u] = xp[(size_t)(tbeg + u) * F];

        float ema;
        int nr;
        if (k == 0) {
            ema = cur[0] * gf;       // t==0 seeding trick (see scan)
            nr = 0;
            va_out[0] = vbf;         // va_trace[:,0,:] = vb
        } else {
            ema = emas[(size_t)k * N + i];
            nr = nrs[(size_t)k * N + i];
        }

        float last_sp = 0.0f;
        for (int t0 = tbeg; t0 < tend; t0 += K2_UNROLL) {
            if (t0 + K2_UNROLL < tend) {
#pragma unroll
                for (int u = 0; u < K2_UNROLL; ++u)
                    nxt[u] = xp[(size_t)(t0 + K2_UNROLL + u) * F];
            }
#pragma unroll
            for (int u = 0; u < K2_UNROLL; ++u) {
                int t = t0 + u;
                float xt = cur[u] * gf;
                float d1 = xt - ema;
                float am = alpha * d1;
                ema = ema + am;
                float d2 = xt - ema;
                float av = Af * d2;
                float vc = vbf - av;       // va_cand
                float dv = vc - vbf;
                bool cross = fabsf(dv) >= thf;
                bool tge = t >= nr;
                bool fired = cross && tge;
                float va_next = (cross || !tge) ? vbf : vc;
                nr = fired ? (t + 1 + rs) : nr;
                float spv = fired ? 1.0f : 0.0f;
                va_out[(size_t)(t + 1) * F] = va_next;
                sp_out[(size_t)t * F] = spv;
                last_sp = spv;
            }
#pragma unroll
            for (int u = 0; u < K2_UNROLL; ++u) cur[u] = nxt[u];
        }
        if (tend == T) sp_out[(size_t)T * F] = last_sp;  // spikes[:,T,:] dup
    }
}

// Fallback: monolithic (used only if ws too small / shape odd).
__global__ __launch_bounds__(64, 1)
void fa_neuron_mono(const float* __restrict__ x,
                    const float* __restrict__ vb,
                    const float* __restrict__ A,
                    const float* __restrict__ th,
                    const float* __restrict__ gain,
                    const float* __restrict__ tref,
                    float* __restrict__ out,
                    int B, int T, int F) {
#pragma clang fp contract(off)
    int tid = blockIdx.x * blockDim.x + threadIdx.x;
    if (tid >= B * F) return;
    int f = tid % F;
    int b = tid / F;
    const float vbf = vb[f], Af = A[f], thf = th[f], gf = gain[f];
    const float alpha = 0.001f;
    int rs = (int)fmaxf(ceilf(tref[f] / 0.05f), 1.0f);
    const float* xp = x + (size_t)b * T * F + f;
    float* va_out   = out + (size_t)b * (T + 1) * F + f;
    float* sp_out   = out + (size_t)B * (T + 1) * F + (size_t)b * (T + 1) * F + f;
    va_out[0] = vbf;
    float ema = 0.0f;
    int nr = 0;
    for (int t = 0; t < T; ++t) {
        float xt = xp[(size_t)t * F] * gf;
        if (t == 0) {
            ema = xt;
        } else {
            float d1 = xt - ema;
            float am = alpha * d1;
            ema = ema + am;
        }
        float d2 = xt - ema;
        float av = Af * d2;
        float vc = vbf - av;
        float dv = vc - vbf;
        bool cross = fabsf(dv) >= thf;
        bool tge = t >= nr;
        bool fired = cross && tge;
        float va_next = (cross || !tge) ? vbf : vc;
        nr = fired ? (t + 1 + rs) : nr;
        float spv = fired ? 1.0f : 0.0f;
        va_out[(size_t)(t + 1) * F] = va_next;
        sp_out[(size_t)t * F] = spv;
        if (t == T - 1) sp_out[(size_t)T * F] = spv;
    }
}

extern "C" void kernel_launch(void* const* d_in, const int* in_sizes, int n_in,
                              void* d_out, int out_size, void* d_ws, size_t ws_size,
                              hipStream_t stream) {
    const float* x    = (const float*)d_in[0];
    const float* vb   = (const float*)d_in[1];
    const float* A    = (const float*)d_in[2];
    const float* th   = (const float*)d_in[3];
    const float* gain = (const float*)d_in[4];
    const float* tref = (const float*)d_in[5];
    float* out = (float*)d_out;

    int F = in_sizes[1];                                   // 512
    long long BF = (long long)out_size / 2 - in_sizes[0];  // B*F
    int B = (int)(BF / F);                                 // 16
    int T = (int)(in_sizes[0] / BF);                       // 4096
    int N = B * F;
    int NG = N / 64;                                       // 128 chain groups

    int nchunks = (T + LCHUNK - 1) / LCHUNK;
    size_t ws_need = (size_t)nchunks * N * (sizeof(float) + sizeof(int))
                   + (size_t)nchunks * NG * sizeof(int);

    bool fused_ok = (ws_size >= ws_need) && (T % LCHUNK == 0) &&
                    (T % TS == 0) && (T / TS >= 4) && (F % 64 == 0) &&
                    (LCHUNK == 4 * TS) && (N % 64 == 0);

    if (!fused_ok) {
        int block = 64;
        int grid = (N + block - 1) / block;
        fa_neuron_mono<<<grid, block, 0, stream>>>(x, vb, A, th, gain, tref, out, B, T, F);
        return;
    }

    float* emas = (float*)d_ws;
    int*   nrs  = (int*)(emas + (size_t)nchunks * N);
    int*   done = (int*)(nrs + (size_t)nchunks * N);

    hipMemsetAsync(done, 0, (size_t)nchunks * NG * sizeof(int), stream);

    int grid = NG + NG * nchunks;   // 128 scan blocks first, then 2048 emit
    fa_fused_kernel<<<grid, 64, 0, stream>>>(x, vb, A, th, gain, tref,
                                             emas, nrs, done, out,
                                             B, T, F, nchunks, NG);
}

// Round 15
// 149.466 us; speedup vs baseline: 1.6272x; 1.6272x over previous
//
#include <hip/hip_runtime.h>
#include <stdint.h>

// FANeuron two-pass (final structure):
//  K1: 128 scan blocks (round-11 asm pipeline, DMA ring, counted vmcnt;
//      STOPS at T-LCHUNK since the last chunk's scan state is unused)
//      + 128 chunk-0 emit blocks (no seeds needed -> zero sync) riding the
//      same grid to use the otherwise-idle CUs. ~1 block/CU.
//  K2: one thread per (chain, chunk k=1..nchunks-1) replays its chunk
//      bit-exactly from the (ema, nr) seed; at the HBM write roofline.

#define LCHUNK 256
#define TS 64
#define DEPTH 4
#define K2_UNROLL 8

typedef const __attribute__((address_space(1))) uint32_t* gptr_t;
typedef __attribute__((address_space(3))) uint32_t* lptr_t;

// 8 bit-exact steps, hand-pipelined. ema/bits carried; vcc clobbered.
#define FA_ASM8(A)                                                         \
    asm volatile(                                                          \
        "v_sub_f32 %[d1], %[a0], %[ema]\n\t"                               \
        "v_mul_f32 %[am], %[al], %[d1]\n\t"                                \
        "v_add_f32 %[ema], %[ema], %[am]\n\t"                              \
        "v_sub_f32 %[d1], %[a1], %[ema]\n\t"                               \
        "v_sub_f32 %[d2], %[a0], %[ema]\n\t"                               \
        "v_mul_f32 %[am], %[al], %[d1]\n\t"                                \
        "v_cmp_le_f32_e64 vcc, %[th], |%[d2]|\n\t"                         \
        "v_add_f32 %[ema], %[ema], %[am]\n\t"                              \
        "v_addc_co_u32 %[bits], vcc, %[bits], %[bits], vcc\n\t"            \
        "v_sub_f32 %[d1], %[a2], %[ema]\n\t"                               \
        "v_sub_f32 %[d2], %[a1], %[ema]\n\t"                               \
        "v_mul_f32 %[am], %[al], %[d1]\n\t"                                \
        "v_cmp_le_f32_e64 vcc, %[th], |%[d2]|\n\t"                         \
        "v_add_f32 %[ema], %[ema], %[am]\n\t"                              \
        "v_addc_co_u32 %[bits], vcc, %[bits], %[bits], vcc\n\t"            \
        "v_sub_f32 %[d1], %[a3], %[ema]\n\t"                               \
        "v_sub_f32 %[d2], %[a2], %[ema]\n\t"                               \
        "v_mul_f32 %[am], %[al], %[d1]\n\t"                                \
        "v_cmp_le_f32_e64 vcc, %[th], |%[d2]|\n\t"                         \
        "v_add_f32 %[ema], %[ema], %[am]\n\t"                              \
        "v_addc_co_u32 %[bits], vcc, %[bits], %[bits], vcc\n\t"            \
        "v_sub_f32 %[d1], %[a4], %[ema]\n\t"                               \
        "v_sub_f32 %[d2], %[a3], %[ema]\n\t"                               \
        "v_mul_f32 %[am], %[al], %[d1]\n\t"                                \
        "v_cmp_le_f32_e64 vcc, %[th], |%[d2]|\n\t"                         \
        "v_add_f32 %[ema], %[ema], %[am]\n\t"                              \
        "v_addc_co_u32 %[bits], vcc, %[bits], %[bits], vcc\n\t"            \
        "v_sub_f32 %[d1], %[a5], %[ema]\n\t"                               \
        "v_sub_f32 %[d2], %[a4], %[ema]\n\t"                               \
        "v_mul_f32 %[am], %[al], %[d1]\n\t"                                \
        "v_cmp_le_f32_e64 vcc, %[th], |%[d2]|\n\t"                         \
        "v_add_f32 %[ema], %[ema], %[am]\n\t"                              \
        "v_addc_co_u32 %[bits], vcc, %[bits], %[bits], vcc\n\t"            \
        "v_sub_f32 %[d1], %[a6], %[ema]\n\t"                               \
        "v_sub_f32 %[d2], %[a5], %[ema]\n\t"                               \
        "v_mul_f32 %[am], %[al], %[d1]\n\t"                                \
        "v_cmp_le_f32_e64 vcc, %[th], |%[d2]|\n\t"                         \
        "v_add_f32 %[ema], %[ema], %[am]\n\t"                              \
        "v_addc_co_u32 %[bits], vcc, %[bits], %[bits], vcc\n\t"            \
        "v_sub_f32 %[d1], %[a7], %[ema]\n\t"                               \
        "v_sub_f32 %[d2], %[a6], %[ema]\n\t"                               \
        "v_mul_f32 %[am], %[al], %[d1]\n\t"                                \
        "v_cmp_le_f32_e64 vcc, %[th], |%[d2]|\n\t"                         \
        "v_add_f32 %[ema], %[ema], %[am]\n\t"                              \
        "v_addc_co_u32 %[bits], vcc, %[bits], %[bits], vcc\n\t"            \
        "v_sub_f32 %[d2], %[a7], %[ema]\n\t"                               \
        "v_cmp_le_f32_e64 vcc, %[th], |%[d2]|\n\t"                         \
        "v_addc_co_u32 %[bits], vcc, %[bits], %[bits], vcc"                \
        : [ema]"+v"(ema), [bits]"+v"(bits),                                \
          [d1]"=&v"(td1), [d2]"=&v"(td2), [am]"=&v"(tam)                   \
        : [a0]"v"((A)[0]), [a1]"v"((A)[1]), [a2]"v"((A)[2]),               \
          [a3]"v"((A)[3]), [a4]"v"((A)[4]), [a5]"v"((A)[5]),               \
          [a6]"v"((A)[6]), [a7]"v"((A)[7]),                                \
          [th]"v"(thf), [al]"s"(alpha)                                     \
        : "vcc")

#define FA_RESOLVE(BASE)                                                   \
    do {                                                                   \
        uint32_t rv = __brev(bits);   /* bit j = cross at (BASE)+j */      \
        int rel = nr - (BASE);                                             \
        uint32_t keep = (rel <= 0) ? rv                                    \
                      : ((rel >= 32) ? 0u : (rv & (0xFFFFFFFFu << rel)));  \
        int j1 = __ffs(keep);                                              \
        nr = keep ? ((BASE) + j1 + rs) : nr;   /* t+1+rs */                \
        bits = 0;                                                          \
    } while (0)

// Emit body: replay [tbeg, tend) from (ema, nr), write va + spikes.
#define FA_EMIT_BODY(TBEG, TEND)                                           \
    do {                                                                   \
        float cur[K2_UNROLL], nxt[K2_UNROLL];                              \
        _Pragma("unroll")                                                  \
        for (int u = 0; u < K2_UNROLL; ++u)                                \
            cur[u] = xp[(size_t)((TBEG) + u) * F];                         \
        if ((TBEG) == 0) {                                                 \
            ema = cur[0] * gf;       /* t==0 seeding trick */              \
            nr = 0;                                                        \
            va_out[0] = vbf;         /* va_trace[:,0,:] = vb */            \
        }                                                                  \
        float last_sp = 0.0f;                                              \
        for (int t0 = (TBEG); t0 < (TEND); t0 += K2_UNROLL) {              \
            if (t0 + K2_UNROLL < (TEND)) {                                 \
                _Pragma("unroll")                                          \
                for (int u = 0; u < K2_UNROLL; ++u)                        \
                    nxt[u] = xp[(size_t)(t0 + K2_UNROLL + u) * F];         \
            }                                                              \
            _Pragma("unroll")                                              \
            for (int u = 0; u < K2_UNROLL; ++u) {                          \
                int t = t0 + u;                                            \
                float xt = cur[u] * gf;                                    \
                float d1 = xt - ema;                                       \
                float am = alpha * d1;                                     \
                ema = ema + am;                                            \
                float d2 = xt - ema;                                       \
                float av = Af * d2;                                        \
                float vc = vbf - av;                                       \
                float dv = vc - vbf;                                       \
                bool cross = fabsf(dv) >= thf;                             \
                bool tge = t >= nr;                                        \
                bool fired = cross && tge;                                 \
                float va_next = (cross || !tge) ? vbf : vc;                \
                nr = fired ? (t + 1 + rs) : nr;                            \
                float spv = fired ? 1.0f : 0.0f;                           \
                va_out[(size_t)(t + 1) * F] = va_next;                     \
                sp_out[(size_t)t * F] = spv;                               \
                last_sp = spv;                                             \
            }                                                              \
            _Pragma("unroll")                                              \
            for (int u = 0; u < K2_UNROLL; ++u) cur[u] = nxt[u];           \
        }                                                                  \
        if ((TEND) == T) sp_out[(size_t)T * F] = last_sp;                  \
    } while (0)

__global__ __launch_bounds__(64)
void fa_scan_kernel(const float* __restrict__ x,
                    const float* __restrict__ vb,
                    const float* __restrict__ A,
                    const float* __restrict__ th,
                    const float* __restrict__ gain,
                    const float* __restrict__ tref,
                    float* __restrict__ emas,   // [nchunks][N] (c>=1 used)
                    int*   __restrict__ nrs,    // [nchunks][N] (c>=1 used)
                    float* __restrict__ out,
                    int B, int T, int F, int NG, int nchunks) {
#pragma clang fp contract(off)
    __shared__ float lds[DEPTH][TS][64];
    const int lane = threadIdx.x;
    const int N = B * F;
    const float alpha = 0.001f;                 // f32(0.05/50)

    if ((int)blockIdx.x >= NG) {
        // -------- chunk-0 emit role (no seeds needed, zero sync) --------
        const int g = (int)blockIdx.x - NG;
        const int i = g * 64 + lane;
        const int f = i % F;
        const int b = i / F;
        const float vbf = vb[f], Af = A[f], thf = th[f], gf = gain[f];
        const int rs = (int)fmaxf(ceilf(tref[f] / 0.05f), 1.0f);
        const float* xp = x + (size_t)b * T * F + f;
        float* va_out   = out + (size_t)b * (T + 1) * F + f;
        float* sp_out   = out + (size_t)B * (T + 1) * F + (size_t)b * (T + 1) * F + f;
        float ema; int nr;
        FA_EMIT_BODY(0, LCHUNK);
        return;
    }

    // ------------------------- scan role -------------------------
    __builtin_amdgcn_s_setprio(1);
    const int gpb = F >> 6;
    const int bi = blockIdx.x;
    const int b = bi / gpb;
    const int f0 = (bi - b * gpb) << 6;
    const int f = f0 + lane;
    const int i = b * F + f;

    const float vbf = vb[f], Af = A[f], thf = th[f], gf = gain[f];
    const int rs = (int)fmaxf(ceilf(tref[f] / 0.05f), 1.0f);

    const float* gsrc0 = x + (size_t)b * T * F + f0
                       + (size_t)(lane >> 4) * F + ((lane & 15) << 2);
    const int ntiles = (T - LCHUNK) / TS;        // last chunk's scan unused

#define ISSUE_TILE(J)                                                         \
    do {                                                                      \
        const float* s_ = gsrc0 + (size_t)(J) * TS * F;                       \
        float* d_ = &lds[(J) & (DEPTH - 1)][0][0];                            \
        _Pragma("unroll")                                                     \
        for (int jj = 0; jj < 16; ++jj) {                                     \
            __builtin_amdgcn_global_load_lds(                                 \
                (gptr_t)(s_ + (size_t)(4 * jj) * F),                          \
                (lptr_t)(d_ + 4 * jj * 64), 16, 0, 0);                        \
        }                                                                     \
    } while (0)

    ISSUE_TILE(0);
    ISSUE_TILE(1);
    ISSUE_TILE(2);

    // fast path requires rs>=31 (max one fire per 32-step window)
    bool fastAll = __all((gf == 1.0f) && (Af == 1.0f) && (vbf == 0.0f) &&
                         (rs >= 31));

    float ema = 0.0f;
    int nr = 0;                                  // ABSOLUTE next-ready step
    uint32_t bits = 0;
    float td1, td2, tam;

    for (int k = 0; k < ntiles; ++k) {
        if (k < ntiles - 2)       asm volatile("s_waitcnt vmcnt(32)" ::: "memory");
        else if (k == ntiles - 2) asm volatile("s_waitcnt vmcnt(16)" ::: "memory");
        else                      asm volatile("s_waitcnt vmcnt(0)"  ::: "memory");
        __builtin_amdgcn_sched_barrier(0);

        const int slot = k & (DEPTH - 1);
        const int tb = k * TS;

        if (k == 0) {
            // bit-exact t==0 seeding: ema = xt(0); step 0 then computes
            // d1=0, E_0=xt, d2=0 -> matches reference exactly.
            float x0 = lds[0][0][lane];
            ema = fastAll ? x0 : (x0 * gf);
        } else if ((k & 3) == 0) {               // LCHUNK/TS == 4
            int c = k >> 2;
            emas[(size_t)c * N + i] = ema;
            nrs[(size_t)c * N + i] = nr;
        }

        if (fastAll) {
            float Ab[8], Bb[8];
#pragma unroll
            for (int j = 0; j < 8; ++j) Ab[j] = lds[slot][j][lane];
#pragma unroll
            for (int j = 0; j < 8; ++j) Bb[j] = lds[slot][8 + j][lane];
            FA_ASM8(Ab);
#pragma unroll
            for (int j = 0; j < 8; ++j) Ab[j] = lds[slot][16 + j][lane];
            FA_ASM8(Bb);
#pragma unroll
            for (int j = 0; j < 8; ++j) Bb[j] = lds[slot][24 + j][lane];
            FA_ASM8(Ab);
#pragma unroll
            for (int j = 0; j < 8; ++j) Ab[j] = lds[slot][32 + j][lane];
            FA_ASM8(Bb);
            FA_RESOLVE(tb);
#pragma unroll
            for (int j = 0; j < 8; ++j) Bb[j] = lds[slot][40 + j][lane];
            FA_ASM8(Ab);
#pragma unroll
            for (int j = 0; j < 8; ++j) Ab[j] = lds[slot][48 + j][lane];
            FA_ASM8(Bb);
#pragma unroll
            for (int j = 0; j < 8; ++j) Bb[j] = lds[slot][56 + j][lane];
            FA_ASM8(Ab);
            FA_ASM8(Bb);
            FA_RESOLVE(tb + 32);
        } else {
            float ra[8], rb[8];
#pragma unroll
            for (int j = 0; j < 8; ++j) ra[j] = lds[slot][j][lane];
#pragma unroll
            for (int t8 = 0; t8 < TS / 8; ++t8) {
                if (t8 < TS / 8 - 1) {
#pragma unroll
                    for (int j = 0; j < 8; ++j)
                        rb[j] = lds[slot][(t8 + 1) * 8 + j][lane];
                }
#pragma unroll
                for (int j = 0; j < 8; ++j) {
                    const int t = tb + t8 * 8 + j;
                    float xt = ra[j] * gf;
                    float d1 = xt - ema;
                    float am = alpha * d1;
                    ema = ema + am;
                    float d2 = xt - ema;
                    float av = Af * d2;
                    float vc = vbf - av;
                    float dv = vc - vbf;
                    bool cross = fabsf(dv) >= thf;
                    bool tge = t >= nr;
                    bool fired = cross && tge;
                    nr = fired ? (t + 1 + rs) : nr;
                }
#pragma unroll
                for (int j = 0; j < 8; ++j) ra[j] = rb[j];
            }
        }

        if (k + 3 < ntiles) ISSUE_TILE(k + 3);
    }
#undef ISSUE_TILE

    // seed for the final chunk (state entering t = T - LCHUNK)
    {
        int c = nchunks - 1;
        emas[(size_t)c * N + i] = ema;
        nrs[(size_t)c * N + i] = nr;
    }
}

__global__ __launch_bounds__(256)
void fa_emit_kernel(const float* __restrict__ x,
                    const float* __restrict__ vb,
                    const float* __restrict__ A,
                    const float* __restrict__ th,
                    const float* __restrict__ gain,
                    const float* __restrict__ tref,
                    const float* __restrict__ emas,
                    const int*   __restrict__ nrs,
                    float* __restrict__ out,
                    int B, int T, int F, int nchunks) {
#pragma clang fp contract(off)
    int N = B * F;
    int tid = blockIdx.x * blockDim.x + threadIdx.x;
    if (tid >= N * (nchunks - 1)) return;
    int i = tid % N;
    int k = tid / N + 1;                         // chunks 1..nchunks-1
    int f = i % F;
    int b = i / F;
    const float vbf = vb[f], Af = A[f], thf = th[f], gf = gain[f];
    const float alpha = 0.001f;
    int rs = (int)fmaxf(ceilf(tref[f] / 0.05f), 1.0f);

    const float* xp = x + (size_t)b * T * F + f;
    float* va_out   = out + (size_t)b * (T + 1) * F + f;
    float* sp_out   = out + (size_t)B * (T + 1) * F + (size_t)b * (T + 1) * F + f;

    int tbeg = k * LCHUNK;
    int tend = tbeg + LCHUNK;
    if (tend > T) tend = T;

    float ema = emas[(size_t)k * N + i];
    int nr = nrs[(size_t)k * N + i];
    FA_EMIT_BODY(tbeg, tend);
}

// Fallback: monolithic (used only if ws too small / shape odd).
__global__ __launch_bounds__(64, 1)
void fa_neuron_mono(const float* __restrict__ x,
                    const float* __restrict__ vb,
                    const float* __restrict__ A,
                    const float* __restrict__ th,
                    const float* __restrict__ gain,
                    const float* __restrict__ tref,
                    float* __restrict__ out,
                    int B, int T, int F) {
#pragma clang fp contract(off)
    int tid = blockIdx.x * blockDim.x + threadIdx.x;
    if (tid >= B * F) return;
    int f = tid % F;
    int b = tid / F;
    const float vbf = vb[f], Af = A[f], thf = th[f], gf = gain[f];
    const float alpha = 0.001f;
    int rs = (int)fmaxf(ceilf(tref[f] / 0.05f), 1.0f);
    const float* xp = x + (size_t)b * T * F + f;
    float* va_out   = out + (size_t)b * (T + 1) * F + f;
    float* sp_out   = out + (size_t)B * (T + 1) * F + (size_t)b * (T + 1) * F + f;
    va_out[0] = vbf;
    float ema = 0.0f;
    int nr = 0;
    for (int t = 0; t < T; ++t) {
        float xt = xp[(size_t)t * F] * gf;
        if (t == 0) {
            ema = xt;
        } else {
            float d1 = xt - ema;
            float am = alpha * d1;
            ema = ema + am;
        }
        float d2 = xt - ema;
        float av = Af * d2;
        float vc = vbf - av;
        float dv = vc - vbf;
        bool cross = fabsf(dv) >= thf;
        bool tge = t >= nr;
        bool fired = cross && tge;
        float va_next = (cross || !tge) ? vbf : vc;
        nr = fired ? (t + 1 + rs) : nr;
        float spv = fired ? 1.0f : 0.0f;
        va_out[(size_t)(t + 1) * F] = va_next;
        sp_out[(size_t)t * F] = spv;
        if (t == T - 1) sp_out[(size_t)T * F] = spv;
    }
}

extern "C" void kernel_launch(void* const* d_in, const int* in_sizes, int n_in,
                              void* d_out, int out_size, void* d_ws, size_t ws_size,
                              hipStream_t stream) {
    const float* x    = (const float*)d_in[0];
    const float* vb   = (const float*)d_in[1];
    const float* A    = (const float*)d_in[2];
    const float* th   = (const float*)d_in[3];
    const float* gain = (const float*)d_in[4];
    const float* tref = (const float*)d_in[5];
    float* out = (float*)d_out;

    int F = in_sizes[1];                                   // 512
    long long BF = (long long)out_size / 2 - in_sizes[0];  // B*F
    int B = (int)(BF / F);                                 // 16
    int T = (int)(in_sizes[0] / BF);                       // 4096
    int N = B * F;
    int NG = N / 64;                                       // 128 chain groups

    int nchunks = (T + LCHUNK - 1) / LCHUNK;
    size_t ws_need = (size_t)nchunks * N * (sizeof(float) + sizeof(int));

    bool tiled_ok = (ws_size >= ws_need) && (T % LCHUNK == 0) &&
                    (T % TS == 0) && (nchunks >= 2) && (F % 64 == 0) &&
                    (LCHUNK == 4 * TS) && ((T - LCHUNK) / TS >= 4) &&
                    (N % 64 == 0);

    if (!tiled_ok) {
        int block = 64;
        int grid = (N + block - 1) / block;
        fa_neuron_mono<<<grid, block, 0, stream>>>(x, vb, A, th, gain, tref, out, B, T, F);
        return;
    }

    float* emas = (float*)d_ws;
    int*   nrs  = (int*)(emas + (size_t)nchunks * N);

    {
        int grid = NG + NG;   // 128 scan blocks + 128 chunk-0 emit blocks
        fa_scan_kernel<<<grid, 64, 0, stream>>>(x, vb, A, th, gain, tref,
                                                emas, nrs, out,
                                                B, T, F, NG, nchunks);
    }
    {
        long long total = (long long)N * (nchunks - 1);
        int block = 256;
        int grid = (int)((total + block - 1) / block);
        fa_emit_kernel<<<grid, block, 0, stream>>>(x, vb, A, th, gain, tref,
                                                   emas, nrs, out, B, T, F,
                                                   nchunks);
    }
}